// Round 6
// baseline (140.772 us; speedup 1.0000x reference)
//
#include <hip/hip_runtime.h>
#include <math.h>

#define NPART 4096
#define NBLK  1024
#define NTHR  256
#define IPB   4     // particles (i) per block: one 64-lane wave per i
#define SMAX  256   // local collision-set cap (expected ~60; own i's pre-seeded)
#define PPT   (NPART / NTHR)   // 16 particles staged per thread

// Constants, rounded exactly as the reference's weak-typed doubles -> f32
constexpr float RORC   = (float)(2.5e-5 + 3.15e-6);    // RO + RC
constexpr float RORC2  = RORC * RORC;
constexpr float RRF    = 8e-6f;
constexpr float RR2    = RRF * RRF;
constexpr float TWORC  = (float)(2.0 * 3.15e-6);
constexpr float TWORC2 = TWORC * TWORC;
constexpr float C21RC  = (float)(2.1 * 3.15e-6);
constexpr float RCAND2 = 1.6e-9f;                      // (4e-5)^2 >= 3-hop chain span
constexpr float C_ROT  = (float)(0.2 * 25.0 * 0.0028);
constexpr float C_RN1  = (float)0.07483314773547883;
constexpr float C_SQDT = (float)0.4472135954999579;
constexpr float C_TRV  = (float)(0.2 * 5e-7);
constexpr float C_HALF = (float)0.7071067811865476;
constexpr float C_SQ2T = (float)1.6733200530681511e-07;
constexpr float EPSF   = 1e-14f;

// ---------------------------------------------------------------------------
// MEASUREMENT ROUND: R1 (best, 82.9us) VERBATIM + a calibrated canary spin
// (2048 x 4 dependent v_xor_b32 ~= 41k cycles ~= +17us @2.4GHz) appended
// after the final store. Purpose: fused_all has been hidden below rocprof's
// top-5 cutoff (39-40us harness fills) since R0; five structure changes
// produced unpredictable deltas. The canary forces fused_all into the top-5
// so its TRUE duration + VALUBusy + Occupancy + FETCH_SIZE become visible,
// and its exact cycle count doubles as an effective-SCLK probe (DVFS test).
// Decision table: dur~52 => real ~35us stall (counters localize it);
// dur~21-25 => harness floor, kernel already ~4-7us; dur>>52 => clock throttle.
// ---------------------------------------------------------------------------
__global__ __launch_bounds__(NTHR, 4) void fused_all(
        const float2* __restrict__ pos, const float2* __restrict__ ori,
        const float* __restrict__ Deltas, const float* __restrict__ rot_noise,
        const float2* __restrict__ trans_noise, float2* __restrict__ out) {
    __shared__ float    sred[2 * NTHR];       // 2 KB mean tree
    __shared__ float    res[5][IPB];
    __shared__ unsigned bmap[NPART / 32];     // 512 B
    __shared__ int      Sidx[SMAX];           // 1 KB
    __shared__ float4   posS4[SMAX / 2];      // 2 KB
    __shared__ int      scnt;
    float2* posS = (float2*)posS4;
    const float4* __restrict__ pos4 = (const float4*)pos;

    const int tid  = threadIdx.x;
    const int il   = tid >> 6;            // own-i 0..3 (one wave each)
    const int lane = tid & 63;
    const int gi   = blockIdx.x * IPB + il;

    if (tid == 0) scnt = IPB;             // slots 0..3 = own i's
    if (tid < IPB) Sidx[tid] = blockIdx.x * IPB + tid;
    if (tid < NPART / 32) bmap[tid] = 0u;

    // ---- mean partials (same per-thread k*NTHR+tid mapping and order);
    //      these coalesced loads also warm L1 for the sweep ----
    float mx = 0.f, my = 0.f;
    #pragma unroll
    for (int k = 0; k < PPT; ++k) {
        const float2 v = pos[k * NTHR + tid];
        mx += v.x; my += v.y;
    }
    sred[tid] = mx; sred[NTHR + tid] = my;
    __syncthreads();                      // sred / bmap / Sidx ready

    // ---- A. brute-force sweep: one wave per own-i, float4 = 2 j's,
    //      straight from global (L1-resident, lane-coalesced) ----
    const float2 pi = pos[gi];
    float nr = 0.f, sx = 0.f, sy = 0.f, oxs = 0.f, oys = 0.f;
    #pragma unroll 2
    for (int t = lane; t < NPART / 2; t += 64) {
        const float4 w = pos4[t];
        const float dx0 = w.x - pi.x, dy0 = w.y - pi.y;
        const float r20 = fmaf(dx0, dx0, dy0 * dy0);
        const float dx1 = w.z - pi.x, dy1 = w.w - pi.y;
        const float r21 = fmaf(dx1, dx1, dy1 * dy1);
        if (r20 <= RCAND2) {              // candidate (incl. self; masked in B)
            const int j = 2 * t;
            atomicOr(&bmap[j >> 5], 1u << (j & 31));
            if (r20 <= RORC2) {           // inside_Ro
                const float2 uj = ori[j];
                oxs += uj.x; oys += uj.y;
                if (r20 <= RR2 && r20 > 0.f) {
                    // in_front fails <=> dot<=0 && cross>=0
                    const float dt_ = fmaf(dx0, uj.x, dy0 * uj.y);
                    const float cr_ = fmaf(dy0, uj.x, -dx0 * uj.y);
                    if (!((dt_ <= 0.f) && (cr_ >= 0.f))) {
                        nr += 1.f; sx += w.x; sy += w.y;
                    }
                }
            }
        }
        if (r21 <= RCAND2) {
            const int j = 2 * t + 1;
            atomicOr(&bmap[j >> 5], 1u << (j & 31));
            if (r21 <= RORC2) {
                const float2 uj = ori[j];
                oxs += uj.x; oys += uj.y;
                if (r21 <= RR2 && r21 > 0.f) {
                    const float dt_ = fmaf(dx1, uj.x, dy1 * uj.y);
                    const float cr_ = fmaf(dy1, uj.x, -dx1 * uj.y);
                    if (!((dt_ <= 0.f) && (cr_ >= 0.f))) {
                        nr += 1.f; sx += w.z; sy += w.w;
                    }
                }
            }
        }
    }
    {   // 64-lane shuffle reduction (whole wave belongs to one i)
        float vals[5] = {nr, sx, sy, oxs, oys};
        #pragma unroll
        for (int q = 0; q < 5; ++q)
            #pragma unroll
            for (int off = 32; off >= 1; off >>= 1)
                vals[q] += __shfl_down(vals[q], off);
        if (lane == 0) {
            res[0][il] = vals[0]; res[1][il] = vals[1]; res[2][il] = vals[2];
            res[3][il] = vals[3]; res[4][il] = vals[4];
        }
    }
    __syncthreads();                      // bmap + res final

    // ---- B. S-compaction from bmap (own-block nibble masked out) ----
    if (tid < NPART / 32) {
        unsigned bits = bmap[tid];
        if (tid == (int)(blockIdx.x >> 3))
            bits &= ~(0xFu << ((blockIdx.x & 7) * 4));
        while (bits) {
            const int b = __ffs(bits) - 1;
            bits &= bits - 1;
            const int slot = atomicAdd(&scnt, 1);
            if (slot < SMAX) Sidx[slot] = tid * 32 + b;
        }
    }
    __syncthreads();
    const int nS = (scnt < SMAX) ? scnt : SMAX;

    // ---- D1. translate S members (reference-exact expression) ----
    if (tid < nS) {
        const int p = Sidx[tid];
        const float2 pq = pos[p];
        const float2 uu = ori[p];
        const float2 tn = trans_noise[p];
        posS[tid] = make_float2(
            pq.x + (C_TRV * uu.x + ((tn.x * C_HALF) * C_SQ2T) * C_SQDT),
            pq.y + (C_TRV * uu.y + ((tn.y * C_HALF) * C_SQ2T) * C_SQDT));
    }

    // ---- C. mean of all positions (identical tree) ----
    for (int s = NTHR / 2; s > 0; s >>= 1) {
        if (tid < s) { sred[tid] += sred[tid + s]; sred[NTHR + tid] += sred[NTHR + tid + s]; }
        __syncthreads();
    }
    const float cmx = sred[0]    * (1.f / NPART);
    const float cmy = sred[NTHR] * (1.f / NPART);

    // ---- C2. per-i epilogue (4 threads; sections 1..4) ----
    if (tid < IPB) {
        const int g2 = blockIdx.x * IPB + tid;
        const float2 p = pos[g2];
        const float2 u = ori[g2];
        const float nrv = res[0][tid], sxv = res[1][tid], syv = res[2][tid];
        const float osx = res[3][tid], osy = res[4][tid];

        const float inv = 1.f / fmaxf(nrv, 1.f);
        const float sg  = (nrv > 0.f) ? 1.f : 0.f;
        const float Sx = sxv * inv - p.x * sg;
        const float Sy = syv * inv - p.y * sg;
        const float dxv = -Sx, dyv = -Sy;        // d = -S

        const float Psx = cmx - p.x;
        const float Psy = cmy - p.y;

        float sd, cd;
        sincosf(Deltas[0], &sd, &cd);
        const float Lx = Psx * cd - Psy * sd;    // Ps * exp(+i*Delta)
        const float Ly = Psx * sd + Psy * cd;
        const float Rx = Psx * cd + Psy * sd;    // Ps * exp(-i*Delta)
        const float Ry = Psy * cd - Psx * sd;

        const float no  = fmaxf(sqrtf(osx * osx + osy * osy + 1e-30f), EPSF);
        const float nl  = fmaxf(sqrtf(Lx * Lx + Ly * Ly + 1e-30f), EPSF);
        const float nrr = fmaxf(sqrtf(Rx * Rx + Ry * Ry + 1e-30f), EPSF);
        const float csl = (Lx * osx + Ly * osy) / (nl * no);
        const float csr = (Rx * osx + Ry * osy) / (nrr * no);
        const bool left = (csl >= csr);
        const float bx = left ? Lx : Rx;
        const float by = left ? Ly : Ry;

        float cx, cy;
        if (dxv != 0.f || dyv != 0.f)    { cx = dxv; cy = dyv; }
        else if (bx != 0.f || by != 0.f) { cx = bx;  cy = by;  }
        else                             { cx = 1.f; cy = 0.f; }

        const float dt_ = cx * u.x + cy * u.y;
        const float cr_ = cy * u.x - cx * u.y;
        const float sin_t = cr_ / sqrtf(dt_ * dt_ + cr_ * cr_);

        const float ang = C_ROT * sin_t + (rot_noise[g2] * C_RN1) * C_SQDT;
        float sa, ca;
        sincosf(ang, &sa, &ca);
        out[1 * NPART + g2] = make_float2(u.x * ca - u.y * sa,
                                          u.x * sa + u.y * ca);
        out[2 * NPART + g2] = make_float2(osx, osy);
        out[3 * NPART + g2] = make_float2(Lx, Ly);
        out[4 * NPART + g2] = make_float2(Rx, Ry);
    }
    __syncthreads();                      // posS complete

    // ---- D2. three local JACOBI passes over S (nS <= 256 == NTHR) ----
    for (int pass = 0; pass < 3; ++pass) {
        float px = 0.f, py = 0.f, ax = 0.f, ay = 0.f;
        const bool mv = (tid < nS);
        if (mv) { px = posS[tid].x; py = posS[tid].y; }
        int b = 0;
        for (; b + 4 <= nS; b += 4) {
            const float4 w0 = posS4[(b >> 1)];
            const float4 w1 = posS4[(b >> 1) + 1];
            const float bxs[4] = {w0.x, w0.z, w1.x, w1.z};
            const float bys[4] = {w0.y, w0.w, w1.y, w1.w};
            #pragma unroll
            for (int s = 0; s < 4; ++s) {
                if (mv) {
                    const float dx = bxs[s] - px, dy = bys[s] - py;
                    const float r2 = fmaf(dx, dx, dy * dy);
                    if (r2 <= TWORC2 && r2 > 0.f) {
                        const float ab = sqrtf(r2);
                        const float sc = (C21RC - ab) * 0.5f / ab;
                        ax = fmaf(dx, sc, ax);
                        ay = fmaf(dy, sc, ay);
                    }
                }
            }
        }
        for (; b < nS; ++b) {
            const float2 pb = posS[b];
            if (mv) {
                const float dx = pb.x - px, dy = pb.y - py;
                const float r2 = fmaf(dx, dx, dy * dy);
                if (r2 <= TWORC2 && r2 > 0.f) {
                    const float ab = sqrtf(r2);
                    const float sc = (C21RC - ab) * 0.5f / ab;
                    ax = fmaf(dx, sc, ax);
                    ay = fmaf(dy, sc, ay);
                }
            }
        }
        __syncthreads();                  // all reads done (Jacobi)
        if (mv) posS[tid] = make_float2(px - ax, py - ay);
        __syncthreads();
    }
    // ---- section 0: own 4 i's are slots 0..3 of S ----
    if (tid < IPB)
        out[0 * NPART + blockIdx.x * IPB + tid] = posS[tid];

    // ---- CANARY: calibrated dependent-VALU spin, all threads/blocks ----
    // 2048 iters x 4 chained v_xor_b32. Dep-chain latency ~4cyc/xor + ~4cyc
    // loop overhead => ~41k cycles ~= 17us @ 2.4GHz. Exact cycle count known
    // => observed time also measures effective SCLK (DVFS probe). Removed
    // next round. asm sink prevents DCE (rule #17).
    {
        int v = tid;
        #pragma unroll 1
        for (int k = 0; k < 2048; ++k) {
            asm volatile(
                "v_xor_b32 %0, %0, %1\n\t"
                "v_xor_b32 %0, %0, %1\n\t"
                "v_xor_b32 %0, %0, %1\n\t"
                "v_xor_b32 %0, %0, %1"
                : "+v"(v) : "v"(k));
        }
        asm volatile("" :: "v"(v));
    }
}

extern "C" void kernel_launch(void* const* d_in, const int* in_sizes, int n_in,
                              void* d_out, int out_size, void* d_ws, size_t ws_size,
                              hipStream_t stream) {
    const float2* pos = (const float2*)d_in[0];
    const float2* ori = (const float2*)d_in[1];
    const float*  del = (const float*)d_in[2];
    const float*  rn  = (const float*)d_in[3];
    const float2* tn  = (const float2*)d_in[4];
    float2* o2 = (float2*)d_out;          // [5][N] float2
    (void)d_ws; (void)ws_size;

    fused_all<<<dim3(NBLK), dim3(NTHR), 0, stream>>>(pos, ori, del, rn, tn, o2);
}

// Round 7
// 84.997 us; speedup vs baseline: 1.6562x; 1.6562x over previous
//
#include <hip/hip_runtime.h>
#include <math.h>

#define NPART 4096
#define NBLK  1024
#define NTHR  256
#define IPB   4     // particles (i) per block: one 64-lane wave per i
#define SMAX  256   // local collision-set cap (expected ~60; own i's pre-seeded)
#define PPT   (NPART / NTHR)   // 16 particles per thread in the mean pass

// Constants, rounded exactly as the reference's weak-typed doubles -> f32
constexpr float RORC   = (float)(2.5e-5 + 3.15e-6);    // RO + RC
constexpr float RORC2  = RORC * RORC;
constexpr float RRF    = 8e-6f;
constexpr float RR2    = RRF * RRF;
constexpr float TWORC  = (float)(2.0 * 3.15e-6);
constexpr float TWORC2 = TWORC * TWORC;
constexpr float C21RC  = (float)(2.1 * 3.15e-6);
constexpr float RCAND2 = 1.6e-9f;                      // (4e-5)^2 >= 3-hop chain span
constexpr float C_ROT  = (float)(0.2 * 25.0 * 0.0028);
constexpr float C_RN1  = (float)0.07483314773547883;
constexpr float C_SQDT = (float)0.4472135954999579;
constexpr float C_TRV  = (float)(0.2 * 5e-7);
constexpr float C_HALF = (float)0.7071067811865476;
constexpr float C_SQ2T = (float)1.6733200530681511e-07;
constexpr float EPSF   = 1e-14f;

// ---------------------------------------------------------------------------
// vs R1 (best 82.9): serial-chain round, informed by R6's canary: effective
// SCLK ~1.0 GHz (not 2.4) and the 39.5us "fill" is a 256MB = L3-size cache
// FLUSHER -> every iteration runs cold. Base kernel ~23us = cold-miss
// latency chain + ~17 barriers, not throughput. Cuts (all bit-exact):
//  (1) entry-warm ori/trans_noise (1 line/thread, asm-sunk) + prefetch
//      pi/Deltas/rot_noise -> mid-kernel scattered reads hit L2 not HBM.
//  (2) S-compaction FUSED into sweep via test-and-set atomicOr (old-value
//      check), own-i bits pre-seeded in bmap -> serial __ffs phase deleted.
//      (Slot order was already atomics-racy in R1; absmax 0.0.)
//  (3) sweep fast-path: fminf(r20,r21)>RCAND2 -> continue (exact skip).
//  (4) barriers 17 -> 10: mean tree s=128/s=64 piggyback, s<=32 as wave-0
//      shuffles (R4's bit-exact ladder); epilogue overlaps Jacobi-1 accum.
//  (5) Jacobi inner predication dropped (px=1e9 for non-members).
// ---------------------------------------------------------------------------
__global__ __launch_bounds__(NTHR, 4) void fused_all(
        const float2* __restrict__ pos, const float2* __restrict__ ori,
        const float* __restrict__ Deltas, const float* __restrict__ rot_noise,
        const float2* __restrict__ trans_noise, float2* __restrict__ out) {
    __shared__ float    sred[2 * NTHR];       // 2 KB mean tree
    __shared__ float    res[5][IPB];
    __shared__ unsigned bmap[NPART / 32];     // 512 B dedup table
    __shared__ int      Sidx[SMAX];           // 1 KB
    __shared__ float4   posS4[SMAX / 2];      // 2 KB
    __shared__ int      scnt;
    float2* posS = (float2*)posS4;
    const float4* __restrict__ pos4 = (const float4*)pos;

    const int tid  = threadIdx.x;
    const int il   = tid >> 6;            // own-i 0..3 (one wave each)
    const int lane = tid & 63;
    const int base = blockIdx.x * IPB;
    const int gi   = base + il;

    // ---- entry: issue every cold load now; warm scattered-read arrays ----
    const float2 pi   = pos[gi];
    const float  delv = Deltas[0];
    float rn_early = 0.f;
    if (tid < IPB) rn_early = rot_noise[base + tid];
    {   // one 128B line per thread covers all 32KB of each array
        const float2 ow = ori[tid * 16];
        const float2 tw = trans_noise[tid * 16];
        asm volatile("" :: "v"(ow.x), "v"(ow.y), "v"(tw.x), "v"(tw.y));
    }

    if (tid == 0) scnt = IPB;             // slots 0..3 = own i's
    if (tid < IPB) Sidx[tid] = base + tid;
    if (tid < NPART / 32) {               // zero + pre-seed own-i bits
        const int seedw = base >> 5;      // all 4 own i's share one word
        bmap[tid] = (tid == seedw) ? (0xFu << (base & 31)) : 0u;
    }

    // ---- mean partials (also warms pos; same mapping/order as R1) ----
    float mx = 0.f, my = 0.f;
    #pragma unroll
    for (int k = 0; k < PPT; ++k) {
        const float2 v = pos[k * NTHR + tid];
        mx += v.x; my += v.y;
    }
    sred[tid] = mx; sred[NTHR + tid] = my;
    __syncthreads();                      // #1: bmap/scnt/Sidx/sred ready

    // ---- A. sweep (one wave per own-i) with fused candidate append ----
    float nr = 0.f, sx = 0.f, sy = 0.f, oxs = 0.f, oys = 0.f;
    #pragma unroll 2
    for (int t = lane; t < NPART / 2; t += 64) {
        const float4 w = pos4[t];
        const float dx0 = w.x - pi.x, dy0 = w.y - pi.y;
        const float r20 = fmaf(dx0, dx0, dy0 * dy0);
        const float dx1 = w.z - pi.x, dy1 = w.w - pi.y;
        const float r21 = fmaf(dx1, dx1, dy1 * dy1);
        if (fminf(r20, r21) > RCAND2) continue;   // exact both-fail skip
        if (r20 <= RCAND2) {
            const int j = 2 * t;
            const unsigned bit = 1u << (j & 31);
            const unsigned old = atomicOr(&bmap[j >> 5], bit);
            if (!(old & bit)) {                   // first discoverer appends
                const int slot = atomicAdd(&scnt, 1);
                if (slot < SMAX) Sidx[slot] = j;
            }
            if (r20 <= RORC2) {           // inside_Ro
                const float2 uj = ori[j];
                oxs += uj.x; oys += uj.y;
                if (r20 <= RR2 && r20 > 0.f) {
                    // in_front fails <=> dot<=0 && cross>=0
                    const float dt_ = fmaf(dx0, uj.x, dy0 * uj.y);
                    const float cr_ = fmaf(dy0, uj.x, -dx0 * uj.y);
                    if (!((dt_ <= 0.f) && (cr_ >= 0.f))) {
                        nr += 1.f; sx += w.x; sy += w.y;
                    }
                }
            }
        }
        if (r21 <= RCAND2) {
            const int j = 2 * t + 1;
            const unsigned bit = 1u << (j & 31);
            const unsigned old = atomicOr(&bmap[j >> 5], bit);
            if (!(old & bit)) {
                const int slot = atomicAdd(&scnt, 1);
                if (slot < SMAX) Sidx[slot] = j;
            }
            if (r21 <= RORC2) {
                const float2 uj = ori[j];
                oxs += uj.x; oys += uj.y;
                if (r21 <= RR2 && r21 > 0.f) {
                    const float dt_ = fmaf(dx1, uj.x, dy1 * uj.y);
                    const float cr_ = fmaf(dy1, uj.x, -dx1 * uj.y);
                    if (!((dt_ <= 0.f) && (cr_ >= 0.f))) {
                        nr += 1.f; sx += w.z; sy += w.w;
                    }
                }
            }
        }
    }
    {   // 64-lane shuffle reduction (whole wave belongs to one i)
        float vals[5] = {nr, sx, sy, oxs, oys};
        #pragma unroll
        for (int q = 0; q < 5; ++q)
            #pragma unroll
            for (int off = 32; off >= 1; off >>= 1)
                vals[q] += __shfl_down(vals[q], off);
        if (lane == 0) {
            res[0][il] = vals[0]; res[1][il] = vals[1]; res[2][il] = vals[2];
            res[3][il] = vals[3]; res[4][il] = vals[4];
        }
    }
    __syncthreads();                      // #2: res/scnt/Sidx/bmap final

    // ---- tree s=128 + D1 translate (scattered reads now L2-warm) ----
    const int nS = (scnt < SMAX) ? scnt : SMAX;
    if (tid < 128) {
        sred[tid]        += sred[tid + 128];
        sred[NTHR + tid] += sred[NTHR + tid + 128];
    }
    if (tid < nS) {
        const int p = Sidx[tid];
        const float2 pq = pos[p];
        const float2 uu = ori[p];
        const float2 tn = trans_noise[p];
        posS[tid] = make_float2(
            pq.x + (C_TRV * uu.x + ((tn.x * C_HALF) * C_SQ2T) * C_SQDT),
            pq.y + (C_TRV * uu.y + ((tn.y * C_HALF) * C_SQ2T) * C_SQDT));
    }
    __syncthreads();                      // #3: s=128 done; posS complete

    if (tid < 64) {
        sred[tid]        += sred[tid + 64];
        sred[NTHR + tid] += sred[NTHR + tid + 64];
    }
    __syncthreads();                      // #4: s=64 done

    // ---- tree s<=32 in wave 0 via shuffles (identical pairwise tree);
    //      waves 1-3 fall through and start Jacobi pass-1 accumulation ----
    float cmx = 0.f, cmy = 0.f;
    if (il == 0) {
        float vx = sred[lane];            // lane < 64
        float vy = sred[NTHR + lane];
        #pragma unroll
        for (int off = 32; off >= 1; off >>= 1) {
            vx += __shfl_down(vx, off);
            vy += __shfl_down(vy, off);
        }
        cmx = __shfl(vx, 0) * (1.f / NPART);
        cmy = __shfl(vy, 0) * (1.f / NPART);
    }

    // ---- C2. per-i epilogue (4 threads = lanes 0..3 of wave 0) ----
    if (tid < IPB) {
        const int g2 = base + tid;
        const float2 p = pos[g2];
        const float2 u = ori[g2];
        const float nrv = res[0][tid], sxv = res[1][tid], syv = res[2][tid];
        const float osx = res[3][tid], osy = res[4][tid];

        const float inv = 1.f / fmaxf(nrv, 1.f);
        const float sg  = (nrv > 0.f) ? 1.f : 0.f;
        const float Sx = sxv * inv - p.x * sg;
        const float Sy = syv * inv - p.y * sg;
        const float dxv = -Sx, dyv = -Sy;        // d = -S

        const float Psx = cmx - p.x;
        const float Psy = cmy - p.y;

        float sd, cd;
        sincosf(delv, &sd, &cd);
        const float Lx = Psx * cd - Psy * sd;    // Ps * exp(+i*Delta)
        const float Ly = Psx * sd + Psy * cd;
        const float Rx = Psx * cd + Psy * sd;    // Ps * exp(-i*Delta)
        const float Ry = Psy * cd - Psx * sd;

        const float no  = fmaxf(sqrtf(osx * osx + osy * osy + 1e-30f), EPSF);
        const float nl  = fmaxf(sqrtf(Lx * Lx + Ly * Ly + 1e-30f), EPSF);
        const float nrr = fmaxf(sqrtf(Rx * Rx + Ry * Ry + 1e-30f), EPSF);
        const float csl = (Lx * osx + Ly * osy) / (nl * no);
        const float csr = (Rx * osx + Ry * osy) / (nrr * no);
        const bool left = (csl >= csr);
        const float bx = left ? Lx : Rx;
        const float by = left ? Ly : Ry;

        float cx, cy;
        if (dxv != 0.f || dyv != 0.f)    { cx = dxv; cy = dyv; }
        else if (bx != 0.f || by != 0.f) { cx = bx;  cy = by;  }
        else                             { cx = 1.f; cy = 0.f; }

        const float dt_ = cx * u.x + cy * u.y;
        const float cr_ = cy * u.x - cx * u.y;
        const float sin_t = cr_ / sqrtf(dt_ * dt_ + cr_ * cr_);

        const float ang = C_ROT * sin_t + (rn_early * C_RN1) * C_SQDT;
        float sa, ca;
        sincosf(ang, &sa, &ca);
        out[1 * NPART + g2] = make_float2(u.x * ca - u.y * sa,
                                          u.x * sa + u.y * ca);
        out[2 * NPART + g2] = make_float2(osx, osy);
        out[3 * NPART + g2] = make_float2(Lx, Ly);
        out[4 * NPART + g2] = make_float2(Rx, Ry);
    }

    // ---- D2. three local JACOBI passes over S (nS <= 256 == NTHR) ----
    for (int pass = 0; pass < 3; ++pass) {
        float px = 1e9f, py = 1e9f, ax = 0.f, ay = 0.f;
        const bool mv = (tid < nS);
        if (mv) { px = posS[tid].x; py = posS[tid].y; }
        int b = 0;
        for (; b + 4 <= nS; b += 4) {
            const float4 w0 = posS4[(b >> 1)];
            const float4 w1 = posS4[(b >> 1) + 1];
            const float bxs[4] = {w0.x, w0.z, w1.x, w1.z};
            const float bys[4] = {w0.y, w0.w, w1.y, w1.w};
            #pragma unroll
            for (int s = 0; s < 4; ++s) {
                const float dx = bxs[s] - px, dy = bys[s] - py;
                const float r2 = fmaf(dx, dx, dy * dy);
                if (r2 <= TWORC2 && r2 > 0.f) {
                    const float ab = sqrtf(r2);
                    const float sc = (C21RC - ab) * 0.5f / ab;
                    ax = fmaf(dx, sc, ax);
                    ay = fmaf(dy, sc, ay);
                }
            }
        }
        for (; b < nS; ++b) {
            const float2 pb = posS[b];
            const float dx = pb.x - px, dy = pb.y - py;
            const float r2 = fmaf(dx, dx, dy * dy);
            if (r2 <= TWORC2 && r2 > 0.f) {
                const float ab = sqrtf(r2);
                const float sc = (C21RC - ab) * 0.5f / ab;
                ax = fmaf(dx, sc, ax);
                ay = fmaf(dy, sc, ay);
            }
        }
        __syncthreads();                  // all reads done (Jacobi)
        if (mv) posS[tid] = make_float2(px - ax, py - ay);
        __syncthreads();
    }
    // ---- section 0: own 4 i's are slots 0..3 of S ----
    if (tid < IPB)
        out[0 * NPART + base + tid] = posS[tid];
}

extern "C" void kernel_launch(void* const* d_in, const int* in_sizes, int n_in,
                              void* d_out, int out_size, void* d_ws, size_t ws_size,
                              hipStream_t stream) {
    const float2* pos = (const float2*)d_in[0];
    const float2* ori = (const float2*)d_in[1];
    const float*  del = (const float*)d_in[2];
    const float*  rn  = (const float*)d_in[3];
    const float2* tn  = (const float2*)d_in[4];
    float2* o2 = (float2*)d_out;          // [5][N] float2
    (void)d_ws; (void)ws_size;

    fused_all<<<dim3(NBLK), dim3(NTHR), 0, stream>>>(pos, ori, del, rn, tn, o2);
}